// Round 3
// baseline (409.083 us; speedup 1.0000x reference)
//
#include <hip/hip_runtime.h>
#include <hip/hip_bf16.h>

#define CC 192

typedef __attribute__((ext_vector_type(8))) short bf16x8;
typedef __attribute__((ext_vector_type(4))) float f32x4;

__device__ __forceinline__ unsigned short f2bf(float f) {
    unsigned int u = __float_as_uint(f);
    u = (u + 0x7fffu + ((u >> 16) & 1u)) >> 16;
    return (unsigned short)u;
}

__device__ __forceinline__ f32x4 mfma16(bf16x8 a, bf16x8 b, f32x4 c) {
    return __builtin_amdgcn_mfma_f32_16x16x32_bf16(a, b, c, 0, 0, 0);
}

// Merged prep: 4 weight transposes (f32 [K][N] -> bf16 [N][K]) + bias expand.
__global__ void k_prep(const float* __restrict__ qkv_w, const float* __restrict__ proj_w,
                       const float* __restrict__ w1, const float* __restrict__ w2,
                       const float* __restrict__ relTab,
                       unsigned short* __restrict__ qkvT, unsigned short* __restrict__ projT,
                       unsigned short* __restrict__ w1T, unsigned short* __restrict__ w2T,
                       float* __restrict__ biasT) {
    int idx = blockIdx.x * blockDim.x + threadIdx.x;
    if (idx < 110592) { int n = idx / 192, k = idx % 192; qkvT[idx] = f2bf(qkv_w[k * 576 + n]); return; }
    idx -= 110592;
    if (idx < 36864)  { int n = idx / 192, k = idx % 192; projT[idx] = f2bf(proj_w[k * 192 + n]); return; }
    idx -= 36864;
    if (idx < 73728)  { int n = idx / 192, k = idx % 192; w1T[idx] = f2bf(w1[k * 384 + n]); return; }
    idx -= 73728;
    if (idx < 73728)  { int n = idx / 384, k = idx % 384; w2T[idx] = f2bf(w2[k * 192 + n]); return; }
    idx -= 73728;
    if (idx < 24576) {
        int h = idx >> 12, i = (idx >> 6) & 63, j = idx & 63;
        int yi = i >> 3, xi = i & 7, yj = j >> 3, xj = j & 7;
        int rel = (yi - yj + 7) * 15 + (xi - xj + 7);
        biasT[idx] = relTab[rel * 6 + h];
    }
}

// One window per block (2048 blocks), 6 waves (one head each in attention phase).
// LDS regions (aliased by phase lifetime):
//   rA [24576 B]: A (swz [64][192] bf16)  ->  VT (swz [6][32][64], 4096 B/head)  ->  AO (swz [64][192])
//   rQ [24576 B]: Q (swz [6][64][32], 4096 B/head) -> P[h<3] (swz [6][64][64], 8192 B/head, spans rQ+rK)
//   rK [24576 B]: K (swz [6][64][32], 4096 B/head) -> P[h>=3]
__global__ __launch_bounds__(384, 3) void k_attn(
    const float* __restrict__ x,
    const float* __restrict__ n1g, const float* __restrict__ n1b,
    const unsigned short* __restrict__ qkvT, const float* __restrict__ qkv_b,
    const unsigned short* __restrict__ projT, const float* __restrict__ proj_b,
    const float* __restrict__ biasTab,
    float* __restrict__ out)
{
    __shared__ __align__(16) char smem[73728];
    __shared__ int sOpos[64];
    char* const rA = smem;
    char* const rQ = smem + 24576;
    char* const rK = smem + 49152;

    const int tid = threadIdx.x;
    const int wid = blockIdx.x;
    const int b = wid >> 6;
    const int win = wid & 63;
    const int wh = win >> 3, ww = win & 7;
    const int lane = tid & 63;
    const int wave = tid >> 6;
    const int lhi = lane >> 4, llo = lane & 15;

    // ---------- Phase 1: LN1 + shifted window gather -> swizzled bf16 A in rA ----------
    if (tid < 256) {
        const int tok = tid >> 2;
        const int ch0 = (tid & 3) * 48;
        const int yi = tok >> 3, xi = tok & 7;
        const int oy = (wh * 8 + yi + 4) & 63;
        const int ox = (ww * 8 + xi + 4) & 63;
        const int base = ((b * 64 + oy) * 64 + ox) * CC;
        if ((tid & 3) == 0) sOpos[tok] = base;
        float v[48];
        float s = 0.f, ss = 0.f;
        #pragma unroll
        for (int i = 0; i < 12; ++i) {
            const float4 f = *(const float4*)(x + base + ch0 + i * 4);
            v[i*4+0]=f.x; v[i*4+1]=f.y; v[i*4+2]=f.z; v[i*4+3]=f.w;
            s  += f.x + f.y + f.z + f.w;
            ss += f.x*f.x + f.y*f.y + f.z*f.z + f.w*f.w;
        }
        s  += __shfl_xor(s, 1);  s  += __shfl_xor(s, 2);
        ss += __shfl_xor(ss, 1); ss += __shfl_xor(ss, 2);
        const float mean = s * (1.f / 192.f);
        const float rstd = rsqrtf(ss * (1.f / 192.f) - mean * mean + 1e-5f);
        char* aBase = rA + tok * 384;
        const int sw = (tok & 7) << 4;
        #pragma unroll
        for (int i = 0; i < 24; ++i) {
            const int c = ch0 + i * 2;
            const float a0 = (v[i*2+0] - mean) * rstd * n1g[c]   + n1b[c];
            const float a1 = (v[i*2+1] - mean) * rstd * n1g[c+1] + n1b[c+1];
            *(unsigned int*)(aBase + ((c * 2) ^ sw)) =
                (unsigned int)f2bf(a0) | ((unsigned int)f2bf(a1) << 16);
        }
    }
    __syncthreads();

    // ---------- Phase 2: QKV GEMM, wave w -> cols [96w, 96w+96) ----------
    {
        const int cbase = wave * 96;
        f32x4 acc[4][6] = {};
        #pragma unroll
        for (int ks = 0; ks < 6; ++ks) {
            bf16x8 af[4];
            const int kbyte = ks * 64 + lhi * 16;
            #pragma unroll
            for (int m = 0; m < 4; ++m) {
                const int row = m * 16 + llo;
                af[m] = *(const bf16x8*)(rA + row * 384 + (kbyte ^ ((row & 7) << 4)));
            }
            #pragma unroll
            for (int n = 0; n < 6; ++n) {
                const int col = cbase + n * 16 + llo;
                const bf16x8 bfr = *(const bf16x8*)(qkvT + col * 192 + ks * 32 + lhi * 8);
                #pragma unroll
                for (int m = 0; m < 4; ++m) acc[m][n] = mfma16(af[m], bfr, acc[m][n]);
            }
        }
        __syncthreads();   // A fully consumed; rA region free for VT
        // epilogue: +bias, scatter to Q/K/VT LDS
        #pragma unroll
        for (int n = 0; n < 6; ++n) {
            const int c0 = cbase + n * 16;
            const int which = c0 / 192;
            const int rem = c0 - which * 192;
            const int h = rem >> 5;
            const int d = (rem & 31) + llo;
            const float bia = qkv_b[c0 + llo];
            #pragma unroll
            for (int m = 0; m < 4; ++m) {
                #pragma unroll
                for (int r = 0; r < 4; ++r) {
                    const int row = m * 16 + lhi * 4 + r;
                    const unsigned short bv = f2bf(acc[m][n][r] + bia);
                    if (which == 0)
                        *(unsigned short*)(rQ + h * 4096 + row * 64 + ((2 * d) ^ ((row & 3) << 4))) = bv;
                    else if (which == 1)
                        *(unsigned short*)(rK + h * 4096 + row * 64 + ((2 * d) ^ ((row & 3) << 4))) = bv;
                    else
                        *(unsigned short*)(rA + h * 4096 + d * 128 + ((2 * row) ^ ((d & 7) << 4))) = bv;
                }
            }
        }
    }
    __syncthreads();

    // ---------- Phase 3: attention (head = wave) ----------
    f32x4 pacc[4][2] = {};
    float rsum[4][4];
    {
        const int h = wave;
        bf16x8 qf[4], kf[4];
        #pragma unroll
        for (int m = 0; m < 4; ++m) {
            const int t = m * 16 + llo;
            qf[m] = *(const bf16x8*)(rQ + h * 4096 + t * 64 + ((lhi * 16) ^ ((t & 3) << 4)));
        }
        #pragma unroll
        for (int n = 0; n < 4; ++n) {
            const int t = n * 16 + llo;
            kf[n] = *(const bf16x8*)(rK + h * 4096 + t * 64 + ((lhi * 16) ^ ((t & 3) << 4)));
        }
        __syncthreads();   // Q/K in registers everywhere; region free for P

        f32x4 sacc[4][4] = {};
        #pragma unroll
        for (int m = 0; m < 4; ++m)
            #pragma unroll
            for (int n = 0; n < 4; ++n)
                sacc[m][n] = mfma16(qf[m], kf[n], sacc[m][n]);

        const bool eH = (wh == 7), eW = (ww == 7);
        int idj[4];
        #pragma unroll
        for (int n = 0; n < 4; ++n) {
            const int j = n * 16 + llo;
            idj[n] = (eH ? ((j >> 3) >= 4 ? 2 : 1) : 0) * 3 + (eW ? ((j & 7) >= 4 ? 2 : 1) : 0);
        }
        const float* bT = biasTab + h * 4096;
        #pragma unroll
        for (int m = 0; m < 4; ++m) {
            #pragma unroll
            for (int r = 0; r < 4; ++r) {
                const int i = m * 16 + lhi * 4 + r;
                const int idi = (eH ? ((i >> 3) >= 4 ? 2 : 1) : 0) * 3 +
                                (eW ? ((i & 7) >= 4 ? 2 : 1) : 0);
                float mx = -1e30f;
                float sv[4];
                #pragma unroll
                for (int n = 0; n < 4; ++n) {
                    const int j = n * 16 + llo;
                    float sc = sacc[m][n][r] * 0.17677669529663687f + bT[i * 64 + j];
                    if (idi != idj[n]) sc -= 100.f;
                    sv[n] = sc;
                    mx = fmaxf(mx, sc);
                }
                mx = fmaxf(mx, __shfl_xor(mx, 1));
                mx = fmaxf(mx, __shfl_xor(mx, 2));
                mx = fmaxf(mx, __shfl_xor(mx, 4));
                mx = fmaxf(mx, __shfl_xor(mx, 8));
                float sum = 0.f;
                unsigned short pb[4];
                #pragma unroll
                for (int n = 0; n < 4; ++n) {
                    const float e = __expf(sv[n] - mx);
                    sum += e;
                    pb[n] = f2bf(e);
                }
                sum += __shfl_xor(sum, 1);
                sum += __shfl_xor(sum, 2);
                sum += __shfl_xor(sum, 4);
                sum += __shfl_xor(sum, 8);
                rsum[m][r] = sum;
                #pragma unroll
                for (int n = 0; n < 4; ++n) {
                    const int j = n * 16 + llo;
                    *(unsigned short*)(rQ + h * 8192 + i * 128 + ((2 * j) ^ ((i & 7) << 4))) = pb[n];
                }
            }
        }
    }
    __syncthreads();   // P visible before PV reads
    {
        const int h = wave;
        #pragma unroll
        for (int ks = 0; ks < 2; ++ks) {
            bf16x8 pf[4];
            #pragma unroll
            for (int m = 0; m < 4; ++m) {
                const int t = m * 16 + llo;
                pf[m] = *(const bf16x8*)(rQ + h * 8192 + t * 128 + ((ks * 64 + lhi * 16) ^ ((t & 7) << 4)));
            }
            #pragma unroll
            for (int n = 0; n < 2; ++n) {
                const int d = n * 16 + llo;
                const bf16x8 vf = *(const bf16x8*)(rA + h * 4096 + d * 128 + ((ks * 64 + lhi * 16) ^ ((d & 7) << 4)));
                #pragma unroll
                for (int m = 0; m < 4; ++m) pacc[m][n] = mfma16(pf[m], vf, pacc[m][n]);
            }
        }
    }
    __syncthreads();   // VT consumed; rA free for AO
    {
        const int h = wave;
        #pragma unroll
        for (int m = 0; m < 4; ++m) {
            #pragma unroll
            for (int n = 0; n < 2; ++n) {
                const int c = h * 32 + n * 16 + llo;
                #pragma unroll
                for (int r = 0; r < 4; ++r) {
                    const int i = m * 16 + lhi * 4 + r;
                    const float v = pacc[m][n][r] / rsum[m][r];
                    *(unsigned short*)(rA + i * 384 + ((c * 2) ^ ((i & 7) << 4))) = f2bf(v);
                }
            }
        }
    }
    __syncthreads();

    // ---------- Phase 4: proj GEMM + residual ----------
    {
        const int cbase = wave * 32;
        f32x4 acc[4][2] = {};
        #pragma unroll
        for (int ks = 0; ks < 6; ++ks) {
            bf16x8 af[4];
            const int kbyte = ks * 64 + lhi * 16;
            #pragma unroll
            for (int m = 0; m < 4; ++m) {
                const int row = m * 16 + llo;
                af[m] = *(const bf16x8*)(rA + row * 384 + (kbyte ^ ((row & 7) << 4)));
            }
            #pragma unroll
            for (int n = 0; n < 2; ++n) {
                const int col = cbase + n * 16 + llo;
                const bf16x8 bfr = *(const bf16x8*)(projT + col * 192 + ks * 32 + lhi * 8);
                #pragma unroll
                for (int m = 0; m < 4; ++m) acc[m][n] = mfma16(af[m], bfr, acc[m][n]);
            }
        }
        #pragma unroll
        for (int n = 0; n < 2; ++n) {
            const int c = cbase + n * 16 + llo;
            const float pb = proj_b[c];
            #pragma unroll
            for (int m = 0; m < 4; ++m) {
                #pragma unroll
                for (int r = 0; r < 4; ++r) {
                    const int i = m * 16 + lhi * 4 + r;
                    const int base = sOpos[i];
                    out[base + c] = x[base + c] + acc[m][n][r] + pb;
                }
            }
        }
    }
}

// 64 tokens per block, 4 waves. In-place on io (= d_out holding h).
// LDS: one 48 KiB region: A (swz [64][192], first 24 KiB) -> G (swz [64][384], all 48 KiB).
__global__ __launch_bounds__(256, 3) void k_mlp(
    const float* __restrict__ n2g, const float* __restrict__ n2b,
    const unsigned short* __restrict__ w1T, const float* __restrict__ b1,
    const unsigned short* __restrict__ w2T, const float* __restrict__ b2,
    float* __restrict__ io)
{
    __shared__ __align__(16) char smem[49152];
    const int tid = threadIdx.x;
    const int lane = tid & 63, wave = tid >> 6;
    const int lhi = lane >> 4, llo = lane & 15;
    const long t0 = (long)blockIdx.x * 64;

    {
        const int tok = tid >> 2;
        const int ch0 = (tid & 3) * 48;
        const float* hp = io + (t0 + tok) * CC;
        float v[48]; float s = 0.f, ss = 0.f;
        #pragma unroll
        for (int i = 0; i < 12; ++i) {
            const float4 f = *(const float4*)(hp + ch0 + i * 4);
            v[i*4]=f.x; v[i*4+1]=f.y; v[i*4+2]=f.z; v[i*4+3]=f.w;
            s += f.x + f.y + f.z + f.w;
            ss += f.x*f.x + f.y*f.y + f.z*f.z + f.w*f.w;
        }
        s  += __shfl_xor(s, 1);  s  += __shfl_xor(s, 2);
        ss += __shfl_xor(ss, 1); ss += __shfl_xor(ss, 2);
        const float mean = s * (1.f / 192.f);
        const float rstd = rsqrtf(ss * (1.f / 192.f) - mean * mean + 1e-5f);
        char* aBase = smem + tok * 384;
        const int sw = (tok & 7) << 4;
        #pragma unroll
        for (int i = 0; i < 24; ++i) {
            const int c = ch0 + i * 2;
            const float a0 = (v[i*2]   - mean) * rstd * n2g[c]   + n2b[c];
            const float a1 = (v[i*2+1] - mean) * rstd * n2g[c+1] + n2b[c+1];
            *(unsigned int*)(aBase + ((c * 2) ^ sw)) =
                (unsigned int)f2bf(a0) | ((unsigned int)f2bf(a1) << 16);
        }
    }
    __syncthreads();
    // GEMM1 (192 -> 384) + exact GELU
    {
        const int cbase = wave * 96;
        f32x4 acc[4][6] = {};
        #pragma unroll
        for (int ks = 0; ks < 6; ++ks) {
            bf16x8 af[4];
            const int kbyte = ks * 64 + lhi * 16;
            #pragma unroll
            for (int m = 0; m < 4; ++m) {
                const int row = m * 16 + llo;
                af[m] = *(const bf16x8*)(smem + row * 384 + (kbyte ^ ((row & 7) << 4)));
            }
            #pragma unroll
            for (int n = 0; n < 6; ++n) {
                const int col = cbase + n * 16 + llo;
                const bf16x8 bfr = *(const bf16x8*)(w1T + col * 192 + ks * 32 + lhi * 8);
                #pragma unroll
                for (int m = 0; m < 4; ++m) acc[m][n] = mfma16(af[m], bfr, acc[m][n]);
            }
        }
        __syncthreads();   // A consumed; region free for G
        #pragma unroll
        for (int n = 0; n < 6; ++n) {
            const int c = cbase + n * 16 + llo;
            const float bb = b1[c];
            #pragma unroll
            for (int m = 0; m < 4; ++m) {
                #pragma unroll
                for (int r = 0; r < 4; ++r) {
                    const int i = m * 16 + lhi * 4 + r;
                    const float u = acc[m][n][r] + bb;
                    const float g = 0.5f * u * (1.f + erff(u * 0.70710678118654752f));
                    *(unsigned short*)(smem + i * 768 + ((c * 2) ^ ((i & 7) << 4))) = f2bf(g);
                }
            }
        }
    }
    __syncthreads();
    // GEMM2 (384 -> 192) + residual, in place
    {
        const int cbase = wave * 48;
        f32x4 acc[4][3] = {};
        #pragma unroll
        for (int ks = 0; ks < 12; ++ks) {
            bf16x8 af[4];
            const int kbyte = ks * 64 + lhi * 16;
            #pragma unroll
            for (int m = 0; m < 4; ++m) {
                const int row = m * 16 + llo;
                af[m] = *(const bf16x8*)(smem + row * 768 + (kbyte ^ ((row & 7) << 4)));
            }
            #pragma unroll
            for (int n = 0; n < 3; ++n) {
                const int col = cbase + n * 16 + llo;
                const bf16x8 bfr = *(const bf16x8*)(w2T + col * 384 + ks * 32 + lhi * 8);
                #pragma unroll
                for (int m = 0; m < 4; ++m) acc[m][n] = mfma16(af[m], bfr, acc[m][n]);
            }
        }
        #pragma unroll
        for (int n = 0; n < 3; ++n) {
            const int c = cbase + n * 16 + llo;
            const float bb = b2[c];
            #pragma unroll
            for (int m = 0; m < 4; ++m) {
                #pragma unroll
                for (int r = 0; r < 4; ++r) {
                    const int i = m * 16 + lhi * 4 + r;
                    float* p = io + (t0 + i) * CC + c;
                    *p = *p + acc[m][n][r] + bb;
                }
            }
        }
    }
}

extern "C" void kernel_launch(void* const* d_in, const int* in_sizes, int n_in,
                              void* d_out, int out_size, void* d_ws, size_t ws_size,
                              hipStream_t stream)
{
    const float* x      = (const float*)d_in[0];
    const float* n1g    = (const float*)d_in[1];
    const float* n1b    = (const float*)d_in[2];
    const float* qkv_w  = (const float*)d_in[3];
    const float* qkv_b  = (const float*)d_in[4];
    const float* proj_w = (const float*)d_in[5];
    const float* proj_b = (const float*)d_in[6];
    const float* relTab = (const float*)d_in[7];
    const float* n2g    = (const float*)d_in[8];
    const float* n2b    = (const float*)d_in[9];
    const float* w1     = (const float*)d_in[10];
    const float* b1     = (const float*)d_in[11];
    const float* w2     = (const float*)d_in[12];
    const float* b2     = (const float*)d_in[13];
    float* out = (float*)d_out;

    char* ws = (char*)d_ws;
    unsigned short* qkvT  = (unsigned short*)(ws);            // [576][192] bf16
    unsigned short* projT = (unsigned short*)(ws + 221184);   // [192][192] bf16
    unsigned short* w1T   = (unsigned short*)(ws + 294912);   // [384][192] bf16
    unsigned short* w2T   = (unsigned short*)(ws + 442368);   // [192][384] bf16
    float*          biasT = (float*)(ws + 589824);            // [6][64][64] f32

    k_prep<<<1248, 256, 0, stream>>>(qkv_w, proj_w, w1, w2, relTab, qkvT, projT, w1T, w2T, biasT);
    k_attn<<<2048, 384, 0, stream>>>(x, n1g, n1b, qkvT, qkv_b, projT, proj_b, biasT, out);
    k_mlp<<<2048, 256, 0, stream>>>(n2g, n2b, w1T, b1, w2T, b2, out);
}

// Round 4
// 350.610 us; speedup vs baseline: 1.1668x; 1.1668x over previous
//
#include <hip/hip_runtime.h>
#include <hip/hip_bf16.h>

#define CC 192

typedef __attribute__((ext_vector_type(8))) short bf16x8;
typedef __attribute__((ext_vector_type(4))) float f32x4;

__device__ __forceinline__ unsigned short f2bf(float f) {
    unsigned int u = __float_as_uint(f);
    u = (u + 0x7fffu + ((u >> 16) & 1u)) >> 16;
    return (unsigned short)u;
}

__device__ __forceinline__ f32x4 mfma16(bf16x8 a, bf16x8 b, f32x4 c) {
    return __builtin_amdgcn_mfma_f32_16x16x32_bf16(a, b, c, 0, 0, 0);
}

// Merged prep: 4 weight transposes (f32 [K][N] -> bf16 [N][K]) + bias expand.
__global__ void k_prep(const float* __restrict__ qkv_w, const float* __restrict__ proj_w,
                       const float* __restrict__ w1, const float* __restrict__ w2,
                       const float* __restrict__ relTab,
                       unsigned short* __restrict__ qkvT, unsigned short* __restrict__ projT,
                       unsigned short* __restrict__ w1T, unsigned short* __restrict__ w2T,
                       float* __restrict__ biasT) {
    int idx = blockIdx.x * blockDim.x + threadIdx.x;
    if (idx < 110592) { int n = idx / 192, k = idx % 192; qkvT[idx] = f2bf(qkv_w[k * 576 + n]); return; }
    idx -= 110592;
    if (idx < 36864)  { int n = idx / 192, k = idx % 192; projT[idx] = f2bf(proj_w[k * 192 + n]); return; }
    idx -= 36864;
    if (idx < 73728)  { int n = idx / 192, k = idx % 192; w1T[idx] = f2bf(w1[k * 384 + n]); return; }
    idx -= 73728;
    if (idx < 73728)  { int n = idx / 384, k = idx % 384; w2T[idx] = f2bf(w2[k * 192 + n]); return; }
    idx -= 73728;
    if (idx < 24576) {
        int h = idx >> 12, i = (idx >> 6) & 63, j = idx & 63;
        int yi = i >> 3, xi = i & 7, yj = j >> 3, xj = j & 7;
        int rel = (yi - yj + 7) * 15 + (xi - xj + 7);
        biasT[idx] = relTab[rel * 6 + h];
    }
}

// One window per block (2048 blocks), 12 waves (2 waves per head in attention).
// LDS regions (aliased by phase lifetime):
//   rA [24576 B]: A (swz [64][192] bf16)  ->  VT (swz [6][32][64], 4096 B/head)  ->  AO (swz [64][192])
//   rQ [24576 B]: Q (swz [6][64][32], 4096 B/head) -> P[h<3] (swz [6][64][64], 8192 B/head, spans rQ+rK)
//   rK [24576 B]: K (swz [6][64][32], 4096 B/head) -> P[h>=3]
__global__ __launch_bounds__(768, 3) void k_attn(
    const float* __restrict__ x,
    const float* __restrict__ n1g, const float* __restrict__ n1b,
    const unsigned short* __restrict__ qkvT, const float* __restrict__ qkv_b,
    const unsigned short* __restrict__ projT, const float* __restrict__ proj_b,
    const float* __restrict__ biasTab,
    float* __restrict__ out)
{
    __shared__ __align__(16) char smem[73728];
    __shared__ int sOpos[64];
    char* const rA = smem;
    char* const rQ = smem + 24576;
    char* const rK = smem + 49152;

    const int tid = threadIdx.x;
    const int wid = blockIdx.x;
    const int b = wid >> 6;
    const int win = wid & 63;
    const int wh = win >> 3, ww = win & 7;
    const int lane = tid & 63;
    const int wave = tid >> 6;
    const int lhi = lane >> 4, llo = lane & 15;

    // ---------- Phase 1: LN1 + shifted window gather (512 threads, 8/token) ----------
    if (tid < 512) {
        const int tok = tid >> 3;
        const int ch0 = (tid & 7) * 24;
        const int yi = tok >> 3, xi = tok & 7;
        const int oy = (wh * 8 + yi + 4) & 63;
        const int ox = (ww * 8 + xi + 4) & 63;
        const int base = ((b * 64 + oy) * 64 + ox) * CC;
        if ((tid & 7) == 0) sOpos[tok] = base;
        float v[24];
        float s = 0.f, ss = 0.f;
        #pragma unroll
        for (int i = 0; i < 6; ++i) {
            const float4 f = *(const float4*)(x + base + ch0 + i * 4);
            v[i*4+0]=f.x; v[i*4+1]=f.y; v[i*4+2]=f.z; v[i*4+3]=f.w;
            s  += f.x + f.y + f.z + f.w;
            ss += f.x*f.x + f.y*f.y + f.z*f.z + f.w*f.w;
        }
        s  += __shfl_xor(s, 1);  s  += __shfl_xor(s, 2);  s  += __shfl_xor(s, 4);
        ss += __shfl_xor(ss, 1); ss += __shfl_xor(ss, 2); ss += __shfl_xor(ss, 4);
        const float mean = s * (1.f / 192.f);
        const float rstd = rsqrtf(ss * (1.f / 192.f) - mean * mean + 1e-5f);
        char* aBase = rA + tok * 384;
        const int sw = (tok & 7) << 4;
        #pragma unroll
        for (int i = 0; i < 12; ++i) {
            const int c = ch0 + i * 2;
            const float a0 = (v[i*2+0] - mean) * rstd * n1g[c]   + n1b[c];
            const float a1 = (v[i*2+1] - mean) * rstd * n1g[c+1] + n1b[c+1];
            *(unsigned int*)(aBase + ((c * 2) ^ sw)) =
                (unsigned int)f2bf(a0) | ((unsigned int)f2bf(a1) << 16);
        }
    }
    __syncthreads();

    // ---------- Phase 2: QKV GEMM, wave w -> cols [48w, 48w+48) ----------
    {
        const int cbase = wave * 48;
        f32x4 acc[4][3] = {};
        #pragma unroll
        for (int ks = 0; ks < 6; ++ks) {
            bf16x8 af[4];
            const int kbyte = ks * 64 + lhi * 16;
            #pragma unroll
            for (int m = 0; m < 4; ++m) {
                const int row = m * 16 + llo;
                af[m] = *(const bf16x8*)(rA + row * 384 + (kbyte ^ ((row & 7) << 4)));
            }
            #pragma unroll
            for (int n = 0; n < 3; ++n) {
                const int col = cbase + n * 16 + llo;
                const bf16x8 bfr = *(const bf16x8*)(qkvT + col * 192 + ks * 32 + lhi * 8);
                #pragma unroll
                for (int m = 0; m < 4; ++m) acc[m][n] = mfma16(af[m], bfr, acc[m][n]);
            }
        }
        __syncthreads();   // A fully consumed; rA region free for VT
        // epilogue: +bias, scatter to Q/K/VT LDS
        #pragma unroll
        for (int n = 0; n < 3; ++n) {
            const int c0 = cbase + n * 16;
            const int which = c0 / 192;
            const int rem = c0 - which * 192;
            const int h = rem >> 5;
            const int d = (rem & 31) + llo;
            const float bia = qkv_b[c0 + llo];
            #pragma unroll
            for (int m = 0; m < 4; ++m) {
                #pragma unroll
                for (int r = 0; r < 4; ++r) {
                    const int row = m * 16 + lhi * 4 + r;
                    const unsigned short bv = f2bf(acc[m][n][r] + bia);
                    if (which == 0)
                        *(unsigned short*)(rQ + h * 4096 + row * 64 + ((2 * d) ^ ((row & 3) << 4))) = bv;
                    else if (which == 1)
                        *(unsigned short*)(rK + h * 4096 + row * 64 + ((2 * d) ^ ((row & 3) << 4))) = bv;
                    else
                        *(unsigned short*)(rA + h * 4096 + d * 128 + ((2 * row) ^ ((d & 7) << 4))) = bv;
                }
            }
        }
    }
    __syncthreads();

    // ---------- Phase 3: attention (head = wave>>1, row-half = wave&1) ----------
    const int h = wave >> 1;
    const int mh = wave & 1;
    f32x4 pacc[2][2] = {};
    float rsum[2][4];
    {
        bf16x8 qf[2], kf[4];
        #pragma unroll
        for (int m = 0; m < 2; ++m) {
            const int t = (mh * 2 + m) * 16 + llo;
            qf[m] = *(const bf16x8*)(rQ + h * 4096 + t * 64 + ((lhi * 16) ^ ((t & 3) << 4)));
        }
        #pragma unroll
        for (int n = 0; n < 4; ++n) {
            const int t = n * 16 + llo;
            kf[n] = *(const bf16x8*)(rK + h * 4096 + t * 64 + ((lhi * 16) ^ ((t & 3) << 4)));
        }
        __syncthreads();   // Q/K in registers everywhere; region free for P

        f32x4 sacc[2][4] = {};
        #pragma unroll
        for (int m = 0; m < 2; ++m)
            #pragma unroll
            for (int n = 0; n < 4; ++n)
                sacc[m][n] = mfma16(qf[m], kf[n], sacc[m][n]);

        const bool eH = (wh == 7), eW = (ww == 7);
        int idj[4];
        #pragma unroll
        for (int n = 0; n < 4; ++n) {
            const int j = n * 16 + llo;
            idj[n] = (eH ? ((j >> 3) >= 4 ? 2 : 1) : 0) * 3 + (eW ? ((j & 7) >= 4 ? 2 : 1) : 0);
        }
        const float* bT = biasTab + h * 4096;
        #pragma unroll
        for (int m = 0; m < 2; ++m) {
            #pragma unroll
            for (int r = 0; r < 4; ++r) {
                const int i = (mh * 2 + m) * 16 + lhi * 4 + r;
                const int idi = (eH ? ((i >> 3) >= 4 ? 2 : 1) : 0) * 3 +
                                (eW ? ((i & 7) >= 4 ? 2 : 1) : 0);
                float mx = -1e30f;
                float sv[4];
                #pragma unroll
                for (int n = 0; n < 4; ++n) {
                    const int j = n * 16 + llo;
                    float sc = sacc[m][n][r] * 0.17677669529663687f + bT[i * 64 + j];
                    if (idi != idj[n]) sc -= 100.f;
                    sv[n] = sc;
                    mx = fmaxf(mx, sc);
                }
                mx = fmaxf(mx, __shfl_xor(mx, 1));
                mx = fmaxf(mx, __shfl_xor(mx, 2));
                mx = fmaxf(mx, __shfl_xor(mx, 4));
                mx = fmaxf(mx, __shfl_xor(mx, 8));
                float sum = 0.f;
                unsigned short pb[4];
                #pragma unroll
                for (int n = 0; n < 4; ++n) {
                    const float e = __expf(sv[n] - mx);
                    sum += e;
                    pb[n] = f2bf(e);
                }
                sum += __shfl_xor(sum, 1);
                sum += __shfl_xor(sum, 2);
                sum += __shfl_xor(sum, 4);
                sum += __shfl_xor(sum, 8);
                rsum[m][r] = sum;
                #pragma unroll
                for (int n = 0; n < 4; ++n) {
                    const int j = n * 16 + llo;
                    *(unsigned short*)(rQ + h * 8192 + i * 128 + ((2 * j) ^ ((i & 7) << 4))) = pb[n];
                }
            }
        }
    }
    // P is wave-private (each wave wrote and reads only its own 32 rows);
    // LDS ops from one wave execute in order -> no barrier needed before PV.
    {
        #pragma unroll
        for (int ks = 0; ks < 2; ++ks) {
            bf16x8 pf[2];
            #pragma unroll
            for (int m = 0; m < 2; ++m) {
                const int t = (mh * 2 + m) * 16 + llo;
                pf[m] = *(const bf16x8*)(rQ + h * 8192 + t * 128 + ((ks * 64 + lhi * 16) ^ ((t & 7) << 4)));
            }
            #pragma unroll
            for (int n = 0; n < 2; ++n) {
                const int d = n * 16 + llo;
                const bf16x8 vf = *(const bf16x8*)(rA + h * 4096 + d * 128 + ((ks * 64 + lhi * 16) ^ ((d & 7) << 4)));
                #pragma unroll
                for (int m = 0; m < 2; ++m) pacc[m][n] = mfma16(pf[m], vf, pacc[m][n]);
            }
        }
    }
    __syncthreads();   // all VT/P reads done; rA free for AO
    {
        #pragma unroll
        for (int m = 0; m < 2; ++m) {
            #pragma unroll
            for (int n = 0; n < 2; ++n) {
                const int c = h * 32 + n * 16 + llo;
                #pragma unroll
                for (int r = 0; r < 4; ++r) {
                    const int i = (mh * 2 + m) * 16 + lhi * 4 + r;
                    const float v = pacc[m][n][r] / rsum[m][r];
                    *(unsigned short*)(rA + i * 384 + ((c * 2) ^ ((i & 7) << 4))) = f2bf(v);
                }
            }
        }
    }
    __syncthreads();

    // ---------- Phase 4: proj GEMM + residual, wave w -> cols [16w, 16w+16) ----------
    {
        const int cbase = wave * 16;
        f32x4 acc[4] = {};
        #pragma unroll
        for (int ks = 0; ks < 6; ++ks) {
            bf16x8 af[4];
            const int kbyte = ks * 64 + lhi * 16;
            #pragma unroll
            for (int m = 0; m < 4; ++m) {
                const int row = m * 16 + llo;
                af[m] = *(const bf16x8*)(rA + row * 384 + (kbyte ^ ((row & 7) << 4)));
            }
            const int col = cbase + llo;
            const bf16x8 bfr = *(const bf16x8*)(projT + col * 192 + ks * 32 + lhi * 8);
            #pragma unroll
            for (int m = 0; m < 4; ++m) acc[m] = mfma16(af[m], bfr, acc[m]);
        }
        const int c = cbase + llo;
        const float pb = proj_b[c];
        #pragma unroll
        for (int m = 0; m < 4; ++m) {
            #pragma unroll
            for (int r = 0; r < 4; ++r) {
                const int i = m * 16 + lhi * 4 + r;
                const int base = sOpos[i];
                out[base + c] = x[base + c] + acc[m][r] + pb;
            }
        }
    }
}

// 64 tokens per block, 8 waves (2 waves per row-half group). In-place on io.
// LDS: one 48 KiB region: A (swz [64][192], first 24 KiB) -> G (swz [64][384], all 48 KiB).
__global__ __launch_bounds__(512, 4) void k_mlp(
    const float* __restrict__ n2g, const float* __restrict__ n2b,
    const unsigned short* __restrict__ w1T, const float* __restrict__ b1,
    const unsigned short* __restrict__ w2T, const float* __restrict__ b2,
    float* __restrict__ io)
{
    __shared__ __align__(16) char smem[49152];
    const int tid = threadIdx.x;
    const int lane = tid & 63, wave = tid >> 6;
    const int lhi = lane >> 4, llo = lane & 15;
    const int mh = wave & 1;
    const long t0 = (long)blockIdx.x * 64;

    {
        const int tok = tid >> 3;
        const int ch0 = (tid & 7) * 24;
        const float* hp = io + (t0 + tok) * CC;
        float v[24]; float s = 0.f, ss = 0.f;
        #pragma unroll
        for (int i = 0; i < 6; ++i) {
            const float4 f = *(const float4*)(hp + ch0 + i * 4);
            v[i*4]=f.x; v[i*4+1]=f.y; v[i*4+2]=f.z; v[i*4+3]=f.w;
            s += f.x + f.y + f.z + f.w;
            ss += f.x*f.x + f.y*f.y + f.z*f.z + f.w*f.w;
        }
        s  += __shfl_xor(s, 1);  s  += __shfl_xor(s, 2);  s  += __shfl_xor(s, 4);
        ss += __shfl_xor(ss, 1); ss += __shfl_xor(ss, 2); ss += __shfl_xor(ss, 4);
        const float mean = s * (1.f / 192.f);
        const float rstd = rsqrtf(ss * (1.f / 192.f) - mean * mean + 1e-5f);
        char* aBase = smem + tok * 384;
        const int sw = (tok & 7) << 4;
        #pragma unroll
        for (int i = 0; i < 12; ++i) {
            const int c = ch0 + i * 2;
            const float a0 = (v[i*2]   - mean) * rstd * n2g[c]   + n2b[c];
            const float a1 = (v[i*2+1] - mean) * rstd * n2g[c+1] + n2b[c+1];
            *(unsigned int*)(aBase + ((c * 2) ^ sw)) =
                (unsigned int)f2bf(a0) | ((unsigned int)f2bf(a1) << 16);
        }
    }
    __syncthreads();
    // GEMM1 (192 -> 384) + exact GELU: wave -> rows [32mh,32mh+32) x cols [(w>>1)*96, +96)
    {
        const int cbase = (wave >> 1) * 96;
        f32x4 acc[2][6] = {};
        #pragma unroll
        for (int ks = 0; ks < 6; ++ks) {
            bf16x8 af[2];
            const int kbyte = ks * 64 + lhi * 16;
            #pragma unroll
            for (int m = 0; m < 2; ++m) {
                const int row = (mh * 2 + m) * 16 + llo;
                af[m] = *(const bf16x8*)(smem + row * 384 + (kbyte ^ ((row & 7) << 4)));
            }
            #pragma unroll
            for (int n = 0; n < 6; ++n) {
                const int col = cbase + n * 16 + llo;
                const bf16x8 bfr = *(const bf16x8*)(w1T + col * 192 + ks * 32 + lhi * 8);
                #pragma unroll
                for (int m = 0; m < 2; ++m) acc[m][n] = mfma16(af[m], bfr, acc[m][n]);
            }
        }
        __syncthreads();   // A consumed; region free for G
        #pragma unroll
        for (int n = 0; n < 6; ++n) {
            const int c = cbase + n * 16 + llo;
            const float bb = b1[c];
            #pragma unroll
            for (int m = 0; m < 2; ++m) {
                #pragma unroll
                for (int r = 0; r < 4; ++r) {
                    const int i = (mh * 2 + m) * 16 + lhi * 4 + r;
                    const float u = acc[m][n][r] + bb;
                    const float g = 0.5f * u * (1.f + erff(u * 0.70710678118654752f));
                    *(unsigned short*)(smem + i * 768 + ((c * 2) ^ ((i & 7) << 4))) = f2bf(g);
                }
            }
        }
    }
    __syncthreads();
    // GEMM2 (384 -> 192) + residual: wave -> rows [32mh,+32) x cols [(w>>1)*48, +48)
    {
        const int cbase = (wave >> 1) * 48;
        f32x4 acc[2][3] = {};
        #pragma unroll
        for (int ks = 0; ks < 12; ++ks) {
            bf16x8 af[2];
            const int kbyte = ks * 64 + lhi * 16;
            #pragma unroll
            for (int m = 0; m < 2; ++m) {
                const int row = (mh * 2 + m) * 16 + llo;
                af[m] = *(const bf16x8*)(smem + row * 768 + (kbyte ^ ((row & 7) << 4)));
            }
            #pragma unroll
            for (int n = 0; n < 3; ++n) {
                const int col = cbase + n * 16 + llo;
                const bf16x8 bfr = *(const bf16x8*)(w2T + col * 384 + ks * 32 + lhi * 8);
                #pragma unroll
                for (int m = 0; m < 2; ++m) acc[m][n] = mfma16(af[m], bfr, acc[m][n]);
            }
        }
        #pragma unroll
        for (int n = 0; n < 3; ++n) {
            const int c = cbase + n * 16 + llo;
            const float bb = b2[c];
            #pragma unroll
            for (int m = 0; m < 2; ++m) {
                #pragma unroll
                for (int r = 0; r < 4; ++r) {
                    const int i = (mh * 2 + m) * 16 + lhi * 4 + r;
                    float* p = io + (t0 + i) * CC + c;
                    *p = *p + acc[m][n][r] + bb;
                }
            }
        }
    }
}

extern "C" void kernel_launch(void* const* d_in, const int* in_sizes, int n_in,
                              void* d_out, int out_size, void* d_ws, size_t ws_size,
                              hipStream_t stream)
{
    const float* x      = (const float*)d_in[0];
    const float* n1g    = (const float*)d_in[1];
    const float* n1b    = (const float*)d_in[2];
    const float* qkv_w  = (const float*)d_in[3];
    const float* qkv_b  = (const float*)d_in[4];
    const float* proj_w = (const float*)d_in[5];
    const float* proj_b = (const float*)d_in[6];
    const float* relTab = (const float*)d_in[7];
    const float* n2g    = (const float*)d_in[8];
    const float* n2b    = (const float*)d_in[9];
    const float* w1     = (const float*)d_in[10];
    const float* b1     = (const float*)d_in[11];
    const float* w2     = (const float*)d_in[12];
    const float* b2     = (const float*)d_in[13];
    float* out = (float*)d_out;

    char* ws = (char*)d_ws;
    unsigned short* qkvT  = (unsigned short*)(ws);            // [576][192] bf16
    unsigned short* projT = (unsigned short*)(ws + 221184);   // [192][192] bf16
    unsigned short* w1T   = (unsigned short*)(ws + 294912);   // [384][192] bf16
    unsigned short* w2T   = (unsigned short*)(ws + 442368);   // [192][384] bf16
    float*          biasT = (float*)(ws + 589824);            // [6][64][64] f32

    k_prep<<<1248, 256, 0, stream>>>(qkv_w, proj_w, w1, w2, relTab, qkvT, projT, w1T, w2T, biasT);
    k_attn<<<2048, 768, 0, stream>>>(x, n1g, n1b, qkvT, qkv_b, projT, proj_b, biasT, out);
    k_mlp<<<2048, 512, 0, stream>>>(n2g, n2b, w1T, b1, w2T, b2, out);
}